// Round 4
// baseline (284.436 us; speedup 1.0000x reference)
//
#include <hip/hip_runtime.h>
#include <hip/hip_fp16.h>
#include <math.h>

// Problem constants
#define NPIX   131072      // B*H*W = 32*64*64
#define KEMB   512
#define DDIM   64
#define HW     4096        // H*W
#define BSTRIDE 262144     // C*H*W

// d_out flat layout (float32): [loss(1) | out(8388608) | perplexity(1) | indices(131072)]
#define OUT_OFF  1
#define PERP_OFF 8388609
#define IDX_OFF  8388610

typedef __attribute__((ext_vector_type(8))) _Float16 f16x8;    // MFMA A/B frag (4 VGPRs)
typedef __attribute__((ext_vector_type(4))) float f32x4;       // MFMA C/D frag

// ws layout: [0,2048) int counts | [2048] float loss_acc | [2052] int done_ctr
// (zeroed by hipMemsetAsync before launch; tables/hnorms now live in LDS only)
//
// LESSONS BAKED IN (R1-R3 post-mortems):
//  - R1/R2: any unified reg cap <128 spills the K-loop live set -> +80MB HBM
//    scratch traffic, MfmaUtil 3%. Keep R0's proven (1024,4) = 128-reg cap.
//  - R3: streaming fragments from L2 inside the K-loop serializes on ~300cyc
//    dependent-load latency at <=16 waves/CU. Tables MUST be LDS-resident.
//  - Proven wins kept: f16 2-split (R2/R3, absmax 0) halves MFMA work vs bf16
//    3-split; fused last-block finalize (R3); R0's 1-block/CU 16-wave shape.
//
// 2-split f16 scheme: x = h + l/2048 + r, |r|<=2^-21|x|.  l pre-scaled by 2^11
// (exact pow2) stays in f16 normal range. Products kept: hh + (h*l'+l'*h)/2048.
// Dropped terms ~1e-4 absolute; the exact fp32 top-2 rescore (R0-verbatim)
// decides the final index, so approx error only matters for top-2 membership.
__global__ __launch_bounds__(1024, 4) void vq_all(
    const float* __restrict__ in, const float* __restrict__ emb,
    int* __restrict__ counts, float* __restrict__ loss_acc,
    int* __restrict__ done_ctr, float* __restrict__ dout)
{
    __shared__ __align__(16) _Float16 eh_l[KEMB * DDIM];   // 64 KB f16 high
    __shared__ __align__(16) _Float16 el_l[KEMB * DDIM];   // 64 KB f16 low*2^11
    __shared__ __align__(16) float hn_lds[KEMB];           // 2 KB
    __shared__ int hist[KEMB];                             // 2 KB
    __shared__ float part[8];
    __shared__ int lastflag;

    const int t    = threadIdx.x;         // 0..1023
    const int lane = t & 63;
    const int wv   = t >> 6;              // wave id 0..15
    const int quad = lane >> 4;
    const int col  = lane & 15;
    const int b    = blockIdx.x >> 3;                        // 8 blocks per image
    const int p0   = ((blockIdx.x & 7) << 9) | (wv << 5);    // first of this wave's 32 px
    const float* xb = in + b * BSTRIDE;

    if (t < KEMB) hist[t] = 0;

    // ---- In-block table build: wave w converts codes [32w, 32w+32).
    // lane = channel; hnorm shuffle-tree bitwise == the old vq_init (R0-proven).
    // Fragment mapping == R7-proven: lane l of tile ct reads code ct*16+(l&15),
    // channels ks*32 + (l>>4)*8 + j  ->  dst = ct*1024 + ks*512 + lane*8 + j.
    for (int i = 0; i < 32; ++i) {
        const int k = wv * 32 + i;
        float x = emb[k * DDIM + lane];
        _Float16 h = (_Float16)x;             // v_cvt_f16_f32, RTNE
        float r1 = x - (float)h;              // exact (Sterbenz)
        _Float16 l = (_Float16)(r1 * 2048.0f);
        const int ct = k >> 4, cl = k & 15;
        const int ks = lane >> 5, qd = (lane >> 3) & 3, j = lane & 7;
        const int dst = ct * 1024 + ks * 512 + (qd * 16 + cl) * 8 + j;
        eh_l[dst] = h;
        el_l[dst] = l;
        float s = x * x;
#pragma unroll
        for (int off = 1; off <= 32; off <<= 1) s += __shfl_xor(s, off, 64);
        if (lane == 0) hn_lds[k] = 0.5f * s;
    }

    // ---- Build x B-fragments: B[n=col][k=quad*8+j], xh/xl[ptile][kstep]
    f16x8 xh[2][2], xl[2][2];
#pragma unroll
    for (int tt = 0; tt < 2; ++tt) {
#pragma unroll
        for (int s = 0; s < 2; ++s) {
            const int ppb = p0 + tt * 16 + col;
            const int c0  = s * 32 + quad * 8;
            f16x8 vh, vl;
#pragma unroll
            for (int j = 0; j < 8; ++j) {
                float x = xb[(c0 + j) * HW + ppb];
                _Float16 h = (_Float16)x;
                float r1 = x - (float)h;
                vh[j] = h;
                vl[j] = (_Float16)(r1 * 2048.0f);
            }
            xh[tt][s] = vh; xl[tt][s] = vl;
        }
    }

    __syncthreads();   // tables + hn + hist ready; K-loop below is barrier-free

    // ---- K-loop over 32 code tiles — pure LDS reads + 12 MFMA per tile
    float v1[2], v2[2]; int k1[2], k2[2];
#pragma unroll
    for (int tt = 0; tt < 2; ++tt) {
        v1[tt] = 3.402823466e38f; v2[tt] = 3.402823466e38f; k1[tt] = 0; k2[tt] = 0;
    }

    for (int ct = 0; ct < 32; ++ct) {
        const int base = ct * 1024 + lane * 8;
        const f16x8 Ah0 = *(const f16x8*)&eh_l[base];
        const f16x8 Ah1 = *(const f16x8*)&eh_l[base + 512];
        const f16x8 Al0 = *(const f16x8*)&el_l[base];
        const f16x8 Al1 = *(const f16x8*)&el_l[base + 512];

        // Per pixel-tile: acc_h = hh terms, acc_l = 2^11*(h*l + l*h) terms.
        // MFMA order bitwise == R3's passing kernel.
        f32x4 a0h = (f32x4){0.f, 0.f, 0.f, 0.f};
        f32x4 a0l = (f32x4){0.f, 0.f, 0.f, 0.f};
        f32x4 a1h = (f32x4){0.f, 0.f, 0.f, 0.f};
        f32x4 a1l = (f32x4){0.f, 0.f, 0.f, 0.f};
        a0h = __builtin_amdgcn_mfma_f32_16x16x32_f16(Ah0, xh[0][0], a0h, 0, 0, 0);
        a0l = __builtin_amdgcn_mfma_f32_16x16x32_f16(Ah0, xl[0][0], a0l, 0, 0, 0);
        a0l = __builtin_amdgcn_mfma_f32_16x16x32_f16(Al0, xh[0][0], a0l, 0, 0, 0);
        a1h = __builtin_amdgcn_mfma_f32_16x16x32_f16(Ah0, xh[1][0], a1h, 0, 0, 0);
        a1l = __builtin_amdgcn_mfma_f32_16x16x32_f16(Ah0, xl[1][0], a1l, 0, 0, 0);
        a1l = __builtin_amdgcn_mfma_f32_16x16x32_f16(Al0, xh[1][0], a1l, 0, 0, 0);
        a0h = __builtin_amdgcn_mfma_f32_16x16x32_f16(Ah1, xh[0][1], a0h, 0, 0, 0);
        a0l = __builtin_amdgcn_mfma_f32_16x16x32_f16(Ah1, xl[0][1], a0l, 0, 0, 0);
        a0l = __builtin_amdgcn_mfma_f32_16x16x32_f16(Al1, xh[0][1], a0l, 0, 0, 0);
        a1h = __builtin_amdgcn_mfma_f32_16x16x32_f16(Ah1, xh[1][1], a1h, 0, 0, 0);
        a1l = __builtin_amdgcn_mfma_f32_16x16x32_f16(Ah1, xl[1][1], a1l, 0, 0, 0);
        a1l = __builtin_amdgcn_mfma_f32_16x16x32_f16(Al1, xh[1][1], a1l, 0, 0, 0);

        const f32x4 hn = *(const f32x4*)&hn_lds[ct * 16 + quad * 4];
#pragma unroll
        for (int r = 0; r < 4; ++r) {
            const int kk = ct * 16 + quad * 4 + r;
            float sc = hn[r] - (a0h[r] + a0l[r] * 4.8828125e-4f);  // + acc_l/2048
            if (sc < v1[0]) { v2[0] = v1[0]; k2[0] = k1[0]; v1[0] = sc; k1[0] = kk; }
            else if (sc < v2[0]) { v2[0] = sc; k2[0] = kk; }
            sc = hn[r] - (a1h[r] + a1l[r] * 4.8828125e-4f);
            if (sc < v1[1]) { v2[1] = v1[1]; k2[1] = k1[1]; v1[1] = sc; k1[1] = kk; }
            else if (sc < v2[1]) { v2[1] = sc; k2[1] = kk; }
        }
    }

    // Cross-quad top-2 merge (lanes l, l^16, l^32 share pixel-col) — R0 verbatim
#pragma unroll
    for (int tt = 0; tt < 2; ++tt) {
#pragma unroll
        for (int off = 16; off <= 32; off <<= 1) {
            float w1 = __shfl_xor(v1[tt], off, 64); int j1 = __shfl_xor(k1[tt], off, 64);
            float w2 = __shfl_xor(v2[tt], off, 64); int j2 = __shfl_xor(k2[tt], off, 64);
            bool aF = (v1[tt] < w1) || (v1[tt] == w1 && k1[tt] < j1);
            float t1 = aF ? v1[tt] : w1;  int u1 = aF ? k1[tt] : j1;
            float tl = aF ? w1 : v1[tt];  int ul = aF ? j1 : k1[tt];      // loser of firsts
            bool bS = (v2[tt] < w2) || (v2[tt] == w2 && k2[tt] < j2);
            float tc = bS ? v2[tt] : w2;  int uc = bS ? k2[tt] : j2;      // better of seconds
            bool lS = (tl < tc) || (tl == tc && ul < uc);
            v1[tt] = t1; k1[tt] = u1;
            v2[tt] = lS ? tl : tc; k2[tt] = lS ? ul : uc;
        }
    }

    // Pixel q = lane&31; lanes l and l+32 handle the same pixel (tt = (l>>4)&1).
    const int q    = lane & 31;
    const int pp   = p0 + q;
    const int tsel = (lane >> 4) & 1;
    const int kA = tsel ? k1[1] : k1[0];
    const int kB = tsel ? k2[1] : k2[0];

    // Exact fp32 rescore, split: lanes<32 score kA, lanes>=32 score kB.
    // Streaming x loads — ops and order bitwise == the passing kernels.
    const int kMine = (lane < 32) ? kA : kB;
    const float4* eM = (const float4*)(emb + kMine * DDIM);
    float a0 = hn_lds[kMine], a1 = 0.f, a2 = 0.f, a3 = 0.f;
#pragma unroll
    for (int i = 0; i < 16; ++i) {
        float4 ea = eM[i];
        const int c = i * 4;
        float x0 = xb[(c + 0) * HW + pp];
        float x1 = xb[(c + 1) * HW + pp];
        float x2 = xb[(c + 2) * HW + pp];
        float x3 = xb[(c + 3) * HW + pp];
        a0 = fmaf(-x0, ea.x, a0);
        a1 = fmaf(-x1, ea.y, a1);
        a2 = fmaf(-x2, ea.z, a2);
        a3 = fmaf(-x3, ea.w, a3);
    }
    const float dMine = (a0 + a1) + (a2 + a3);
    const float dOth  = __shfl_xor(dMine, 32, 64);
    const float dA = (lane < 32) ? dMine : dOth;
    const float dB = (lane < 32) ? dOth  : dMine;
    const int myk = (dB < dA || (dB == dA && kB < kA)) ? kB : kA;

    float lsum = 0.f;
    if (lane < 32) {
        dout[IDX_OFF + b * HW + pp] = (float)myk;
        atomicAdd(&hist[myk], 1);
        const float4* qrow = (const float4*)(emb + myk * DDIM);
        float* ob = dout + OUT_OFF + b * BSTRIDE;
#pragma unroll
        for (int i = 0; i < 16; ++i) {
            float4 qv = qrow[i];
            const int c = i * 4;
            float x0 = xb[(c + 0) * HW + pp];   // L1-warm reload (just read above)
            float x1 = xb[(c + 1) * HW + pp];
            float x2 = xb[(c + 2) * HW + pp];
            float x3 = xb[(c + 3) * HW + pp];
            float d0 = qv.x - x0;
            float d1 = qv.y - x1;
            float d2 = qv.z - x2;
            float d3 = qv.w - x3;
            lsum += d0 * d0 + d1 * d1 + d2 * d2 + d3 * d3;
            ob[(c + 0) * HW + pp] = x0 + d0;    // reference rounding: x + (q - x)
            ob[(c + 1) * HW + pp] = x1 + d1;
            ob[(c + 2) * HW + pp] = x2 + d2;
            ob[(c + 3) * HW + pp] = x3 + d3;
        }
    }
    for (int off = 32; off > 0; off >>= 1) lsum += __shfl_down(lsum, off, 64);
    if (lane == 0) atomicAdd(loss_acc, lsum);

    __syncthreads();
    if (t < KEMB) {
        int v = hist[t];
        if (v) atomicAdd(&counts[t], v);
    }

    // ---- Fused finalize: last block to arrive computes perplexity + loss.
    __threadfence();
    __syncthreads();
    if (t == 0) lastflag = (atomicAdd(done_ctr, 1) == 255) ? 1 : 0;
    __syncthreads();
    if (lastflag) {
        if (t < KEMB) {
            int cnt = atomicAdd(&counts[t], 0);   // device-coherent read
            float pa = (float)cnt / (float)NPIX;
            float v = pa * logf(pa + 1e-10f);
#pragma unroll
            for (int off = 1; off <= 32; off <<= 1) v += __shfl_xor(v, off, 64);
            if ((t & 63) == 0) part[t >> 6] = v;
        }
        __syncthreads();
        if (t == 0) {
            float s = 0.f;
#pragma unroll
            for (int i = 0; i < 8; ++i) s += part[i];
            dout[PERP_OFF] = expf(-s);
            dout[0] = 0.25f * atomicAdd(loss_acc, 0.0f) / 8388608.0f;
        }
    }
}

extern "C" void kernel_launch(void* const* d_in, const int* in_sizes, int n_in,
                              void* d_out, int out_size, void* d_ws, size_t ws_size,
                              hipStream_t stream) {
    const float* in  = (const float*)d_in[0];   // 8388608 elems
    const float* emb = (const float*)d_in[1];   // 32768 elems
    float* dout = (float*)d_out;
    int*   counts   = (int*)d_ws;
    float* loss_acc = (float*)((char*)d_ws + 2048);
    int*   done_ctr = (int*)((char*)d_ws + 2052);

    hipMemsetAsync(d_ws, 0, 2112, stream);   // counts + loss_acc + done_ctr
    vq_all<<<256, 1024, 0, stream>>>(in, emb, counts, loss_acc, done_ctr, dout);
}

// Round 5
// 266.381 us; speedup vs baseline: 1.0678x; 1.0678x over previous
//
#include <hip/hip_runtime.h>
#include <hip/hip_fp16.h>
#include <math.h>

// Problem constants
#define NPIX   131072      // B*H*W = 32*64*64
#define KEMB   512
#define DDIM   64
#define HW     4096        // H*W
#define BSTRIDE 262144     // C*H*W

// d_out flat layout (float32): [loss(1) | out(8388608) | perplexity(1) | indices(131072)]
#define OUT_OFF  1
#define PERP_OFF 8388609
#define IDX_OFF  8388610

typedef __attribute__((ext_vector_type(8))) _Float16 f16x8;    // MFMA A/B frag (4 VGPRs)
typedef __attribute__((ext_vector_type(4))) float f32x4;       // MFMA C/D frag

// ws layout: [0,2048) int counts | [2048,4096) float hnorms | [4096] loss |
//            [4160] done_ctr | [8192,73728) eh_t (f16 high, frag-linear, 64KB) |
//            [73728,139264) el_t (f16 low pre-scaled by 2^11, frag-linear, 64KB)
//
// SESSION LEDGER (what is PROVEN on this problem):
//  - R0 shell = fastest observed: separate tiny init kernel -> frag-ordered
//    global tables -> wide linear 16B/lane LDS staging -> barrier-free K-loop,
//    256x1024 @ launch_bounds(1024,4). vq_main 107us.
//  - R1/R2: any reg cap < 128 spills the K-loop (scratch: +50..80MB HBM). Never.
//  - R3: global fragment streams in the K-loop serialize on load latency. Never.
//  - R4: in-block table build = 8-way-conflicted u16 scatters (bank-conflict
//    31K->1.6M) + serial shfl chains before the barrier. Never. BUT R4 proved
//    the 12-MFMA f16 2-split K-loop body itself is sound (absmax 0, MFMA pipe
//    time exactly halved) and the fused last-block finalize is clean (R3/R4).
//  - This kernel: R0 shell + f16 2-split both-tables-LDS + fused finalize.
//
// 2-split f16 scheme (absmax 0 in R2/R3/R4): x = h + l/2048 + r, |r|<=2^-21|x|.
// l pre-scaled by 2^11 (exact pow2) stays in f16 normal range. Products kept:
// hh + (h*l'+l'*h)/2048; dropped terms ~1e-4 absolute, and the exact fp32
// top-2 rescore (R0-verbatim) decides the final index.
__global__ void vq_init(const float* __restrict__ emb, int* __restrict__ counts,
                        float* __restrict__ hnorms, float* __restrict__ loss_acc,
                        int* __restrict__ done_ctr,
                        unsigned short* __restrict__ eh_t,
                        unsigned short* __restrict__ el_t) {
    const int k = blockIdx.x;             // code
    const int c = threadIdx.x;            // channel
    const int ct = k >> 4, cl = k & 15;
    const int ks = c >> 5, qd = (c >> 3) & 3, j = c & 7;
    float x = emb[k * DDIM + c];
    _Float16 h = (_Float16)x;             // v_cvt_f16_f32, RTNE
    float r1 = x - (float)h;              // exact (Sterbenz)
    _Float16 l = (_Float16)(r1 * 2048.0f);
    const int dst = ct * 1024 + ks * 512 + (qd * 16 + cl) * 8 + j;
    ((_Float16*)eh_t)[dst] = h;
    ((_Float16*)el_t)[dst] = l;
    float s = x * x;
#pragma unroll
    for (int off = 1; off <= 32; off <<= 1) s += __shfl_xor(s, off, 64);
    if (c == 0) {
        hnorms[k] = 0.5f * s;
        counts[k] = 0;
        if (k == 0) { *loss_acc = 0.f; *done_ctr = 0; }
    }
}

// 256 blocks x 1024 threads, 1 block/CU, 16 waves (R0 shape). LDS 132KB:
// both f16 tables resident -> K-loop is pure LDS + 12 MFMA/tile, barrier-free.
__global__ __launch_bounds__(1024, 4) void vq_main(
    const float* __restrict__ in, const float* __restrict__ emb,
    const unsigned short* __restrict__ eh_t, const unsigned short* __restrict__ el_t,
    const float* __restrict__ hnorms, int* __restrict__ counts,
    float* __restrict__ loss_acc, int* __restrict__ done_ctr,
    float* __restrict__ dout)
{
    __shared__ __align__(16) _Float16 eh_l[KEMB * DDIM];   // 64 KB
    __shared__ __align__(16) _Float16 el_l[KEMB * DDIM];   // 64 KB
    __shared__ __align__(16) float hn_lds[KEMB];           // 2 KB
    __shared__ int hist[KEMB];                             // 2 KB
    __shared__ float part[8];
    __shared__ int lastflag;

    const int t    = threadIdx.x;         // 0..1023
    const int lane = t & 63;
    const int wv   = t >> 6;              // wave id 0..15
    const int quad = lane >> 4;
    const int col  = lane & 15;
    const int b    = blockIdx.x >> 3;                        // 8 blocks per image
    const int p0   = ((blockIdx.x & 7) << 9) | (wv << 5);    // first of this wave's 32 px
    const float* xb = in + b * BSTRIDE;

    if (t < KEMB) hist[t] = 0;
    if (t < 128) ((float4*)hn_lds)[t] = ((const float4*)hnorms)[t];

    // ---- Stage both tables into LDS: linear 16B/lane copies (R2-proven,
    // conflict-free: byte addr = 16*t, same pattern as the K-loop reads).
#pragma unroll
    for (int i = 0; i < 4; ++i) {
        const int f = (t + i * 1024) * 8;
        *(f16x8*)&eh_l[f] = *(const f16x8*)((const _Float16*)eh_t + f);
        *(f16x8*)&el_l[f] = *(const f16x8*)((const _Float16*)el_t + f);
    }

    // ---- Build x B-fragments: B[n=col][k=quad*8+j], xh/xl[ptile][kstep]
    f16x8 xh[2][2], xl[2][2];
#pragma unroll
    for (int tt = 0; tt < 2; ++tt) {
#pragma unroll
        for (int s = 0; s < 2; ++s) {
            const int ppb = p0 + tt * 16 + col;
            const int c0  = s * 32 + quad * 8;
            f16x8 vh, vl;
#pragma unroll
            for (int j = 0; j < 8; ++j) {
                float x = xb[(c0 + j) * HW + ppb];
                _Float16 h = (_Float16)x;
                float r1 = x - (float)h;
                vh[j] = h;
                vl[j] = (_Float16)(r1 * 2048.0f);
            }
            xh[tt][s] = vh; xl[tt][s] = vl;
        }
    }

    __syncthreads();   // tables + hn + hist ready; K-loop below is barrier-free

    // ---- K-loop over 32 code tiles — pure LDS reads + 12 MFMA per tile
    // (body verbatim == R4's passing kernel)
    float v1[2], v2[2]; int k1[2], k2[2];
#pragma unroll
    for (int tt = 0; tt < 2; ++tt) {
        v1[tt] = 3.402823466e38f; v2[tt] = 3.402823466e38f; k1[tt] = 0; k2[tt] = 0;
    }

    for (int ct = 0; ct < 32; ++ct) {
        const int base = ct * 1024 + lane * 8;
        const f16x8 Ah0 = *(const f16x8*)&eh_l[base];
        const f16x8 Ah1 = *(const f16x8*)&eh_l[base + 512];
        const f16x8 Al0 = *(const f16x8*)&el_l[base];
        const f16x8 Al1 = *(const f16x8*)&el_l[base + 512];

        f32x4 a0h = (f32x4){0.f, 0.f, 0.f, 0.f};
        f32x4 a0l = (f32x4){0.f, 0.f, 0.f, 0.f};
        f32x4 a1h = (f32x4){0.f, 0.f, 0.f, 0.f};
        f32x4 a1l = (f32x4){0.f, 0.f, 0.f, 0.f};
        a0h = __builtin_amdgcn_mfma_f32_16x16x32_f16(Ah0, xh[0][0], a0h, 0, 0, 0);
        a0l = __builtin_amdgcn_mfma_f32_16x16x32_f16(Ah0, xl[0][0], a0l, 0, 0, 0);
        a0l = __builtin_amdgcn_mfma_f32_16x16x32_f16(Al0, xh[0][0], a0l, 0, 0, 0);
        a1h = __builtin_amdgcn_mfma_f32_16x16x32_f16(Ah0, xh[1][0], a1h, 0, 0, 0);
        a1l = __builtin_amdgcn_mfma_f32_16x16x32_f16(Ah0, xl[1][0], a1l, 0, 0, 0);
        a1l = __builtin_amdgcn_mfma_f32_16x16x32_f16(Al0, xh[1][0], a1l, 0, 0, 0);
        a0h = __builtin_amdgcn_mfma_f32_16x16x32_f16(Ah1, xh[0][1], a0h, 0, 0, 0);
        a0l = __builtin_amdgcn_mfma_f32_16x16x32_f16(Ah1, xl[0][1], a0l, 0, 0, 0);
        a0l = __builtin_amdgcn_mfma_f32_16x16x32_f16(Al1, xh[0][1], a0l, 0, 0, 0);
        a1h = __builtin_amdgcn_mfma_f32_16x16x32_f16(Ah1, xh[1][1], a1h, 0, 0, 0);
        a1l = __builtin_amdgcn_mfma_f32_16x16x32_f16(Ah1, xl[1][1], a1l, 0, 0, 0);
        a1l = __builtin_amdgcn_mfma_f32_16x16x32_f16(Al1, xh[1][1], a1l, 0, 0, 0);

        const f32x4 hn = *(const f32x4*)&hn_lds[ct * 16 + quad * 4];
#pragma unroll
        for (int r = 0; r < 4; ++r) {
            const int kk = ct * 16 + quad * 4 + r;
            float sc = hn[r] - (a0h[r] + a0l[r] * 4.8828125e-4f);  // + acc_l/2048
            if (sc < v1[0]) { v2[0] = v1[0]; k2[0] = k1[0]; v1[0] = sc; k1[0] = kk; }
            else if (sc < v2[0]) { v2[0] = sc; k2[0] = kk; }
            sc = hn[r] - (a1h[r] + a1l[r] * 4.8828125e-4f);
            if (sc < v1[1]) { v2[1] = v1[1]; k2[1] = k1[1]; v1[1] = sc; k1[1] = kk; }
            else if (sc < v2[1]) { v2[1] = sc; k2[1] = kk; }
        }
    }

    // Cross-quad top-2 merge (lanes l, l^16, l^32 share pixel-col) — R0 verbatim
#pragma unroll
    for (int tt = 0; tt < 2; ++tt) {
#pragma unroll
        for (int off = 16; off <= 32; off <<= 1) {
            float w1 = __shfl_xor(v1[tt], off, 64); int j1 = __shfl_xor(k1[tt], off, 64);
            float w2 = __shfl_xor(v2[tt], off, 64); int j2 = __shfl_xor(k2[tt], off, 64);
            bool aF = (v1[tt] < w1) || (v1[tt] == w1 && k1[tt] < j1);
            float t1 = aF ? v1[tt] : w1;  int u1 = aF ? k1[tt] : j1;
            float tl = aF ? w1 : v1[tt];  int ul = aF ? j1 : k1[tt];      // loser of firsts
            bool bS = (v2[tt] < w2) || (v2[tt] == w2 && k2[tt] < j2);
            float tc = bS ? v2[tt] : w2;  int uc = bS ? j2 : k2[tt];      // placeholder
            // (fixed below — keep exact R0 semantics)
            tc = bS ? v2[tt] : w2;  uc = bS ? k2[tt] : j2;                // better of seconds
            bool lS = (tl < tc) || (tl == tc && ul < uc);
            v1[tt] = t1; k1[tt] = u1;
            v2[tt] = lS ? tl : tc; k2[tt] = lS ? ul : uc;
        }
    }

    // Pixel q = lane&31; lanes l and l+32 handle the same pixel (tt = (l>>4)&1).
    const int q    = lane & 31;
    const int pp   = p0 + q;
    const int tsel = (lane >> 4) & 1;
    const int kA = tsel ? k1[1] : k1[0];
    const int kB = tsel ? k2[1] : k2[0];

    // Exact fp32 rescore, split: lanes<32 score kA, lanes>=32 score kB.
    // Streaming x loads — ops and order bitwise == the passing kernels.
    const int kMine = (lane < 32) ? kA : kB;
    const float4* eM = (const float4*)(emb + kMine * DDIM);
    float a0 = hn_lds[kMine], a1 = 0.f, a2 = 0.f, a3 = 0.f;
#pragma unroll
    for (int i = 0; i < 16; ++i) {
        float4 ea = eM[i];
        const int c = i * 4;
        float x0 = xb[(c + 0) * HW + pp];
        float x1 = xb[(c + 1) * HW + pp];
        float x2 = xb[(c + 2) * HW + pp];
        float x3 = xb[(c + 3) * HW + pp];
        a0 = fmaf(-x0, ea.x, a0);
        a1 = fmaf(-x1, ea.y, a1);
        a2 = fmaf(-x2, ea.z, a2);
        a3 = fmaf(-x3, ea.w, a3);
    }
    const float dMine = (a0 + a1) + (a2 + a3);
    const float dOth  = __shfl_xor(dMine, 32, 64);
    const float dA = (lane < 32) ? dMine : dOth;
    const float dB = (lane < 32) ? dOth  : dMine;
    const int myk = (dB < dA || (dB == dA && kB < kA)) ? kB : kA;

    float lsum = 0.f;
    if (lane < 32) {
        dout[IDX_OFF + b * HW + pp] = (float)myk;
        atomicAdd(&hist[myk], 1);
        const float4* qrow = (const float4*)(emb + myk * DDIM);
        float* ob = dout + OUT_OFF + b * BSTRIDE;
#pragma unroll
        for (int i = 0; i < 16; ++i) {
            float4 qv = qrow[i];
            const int c = i * 4;
            float x0 = xb[(c + 0) * HW + pp];   // L1-warm reload (just read above)
            float x1 = xb[(c + 1) * HW + pp];
            float x2 = xb[(c + 2) * HW + pp];
            float x3 = xb[(c + 3) * HW + pp];
            float d0 = qv.x - x0;
            float d1 = qv.y - x1;
            float d2 = qv.z - x2;
            float d3 = qv.w - x3;
            lsum += d0 * d0 + d1 * d1 + d2 * d2 + d3 * d3;
            ob[(c + 0) * HW + pp] = x0 + d0;    // reference rounding: x + (q - x)
            ob[(c + 1) * HW + pp] = x1 + d1;
            ob[(c + 2) * HW + pp] = x2 + d2;
            ob[(c + 3) * HW + pp] = x3 + d3;
        }
    }
    for (int off = 32; off > 0; off >>= 1) lsum += __shfl_down(lsum, off, 64);
    if (lane == 0) atomicAdd(loss_acc, lsum);

    __syncthreads();
    if (t < KEMB) {
        int v = hist[t];
        if (v) atomicAdd(&counts[t], v);
    }

    // ---- Fused finalize: last block to arrive computes perplexity + loss.
    __threadfence();
    __syncthreads();
    if (t == 0) lastflag = (atomicAdd(done_ctr, 1) == 255) ? 1 : 0;
    __syncthreads();
    if (lastflag) {
        if (t < KEMB) {
            int cnt = atomicAdd(&counts[t], 0);   // device-coherent read
            float pa = (float)cnt / (float)NPIX;
            float v = pa * logf(pa + 1e-10f);
#pragma unroll
            for (int off = 1; off <= 32; off <<= 1) v += __shfl_xor(v, off, 64);
            if ((t & 63) == 0) part[t >> 6] = v;
        }
        __syncthreads();
        if (t == 0) {
            float s = 0.f;
#pragma unroll
            for (int i = 0; i < 8; ++i) s += part[i];
            dout[PERP_OFF] = expf(-s);
            dout[0] = 0.25f * atomicAdd(loss_acc, 0.0f) / 8388608.0f;
        }
    }
}

extern "C" void kernel_launch(void* const* d_in, const int* in_sizes, int n_in,
                              void* d_out, int out_size, void* d_ws, size_t ws_size,
                              hipStream_t stream) {
    const float* in  = (const float*)d_in[0];   // 8388608 elems
    const float* emb = (const float*)d_in[1];   // 32768 elems
    float* dout = (float*)d_out;
    int*   counts   = (int*)d_ws;
    float* hnorms   = (float*)((char*)d_ws + 2048);
    float* loss_acc = (float*)((char*)d_ws + 4096);
    int*   done_ctr = (int*)((char*)d_ws + 4160);
    unsigned short* eh_t = (unsigned short*)((char*)d_ws + 8192);
    unsigned short* el_t = eh_t + KEMB * DDIM;   // 64 KB scaled-l table

    vq_init<<<512, 64, 0, stream>>>(emb, counts, hnorms, loss_acc, done_ctr, eh_t, el_t);
    vq_main<<<256, 1024, 0, stream>>>(in, emb, eh_t, el_t, hnorms, counts, loss_acc, done_ctr, dout);
}

// Round 6
// 175.237 us; speedup vs baseline: 1.6231x; 1.5201x over previous
//
#include <hip/hip_runtime.h>
#include <math.h>

// Problem constants
#define NPIX   131072      // B*H*W = 32*64*64
#define KEMB   512
#define DDIM   64
#define HW     4096        // H*W
#define BSTRIDE 262144     // C*H*W

// d_out flat layout (float32): [loss(1) | out(8388608) | perplexity(1) | indices(131072)]
#define OUT_OFF  1
#define PERP_OFF 8388609
#define IDX_OFF  8388610

typedef __attribute__((ext_vector_type(8))) short bf16x8;   // 8 bf16 = 4 VGPRs (MFMA A/B frag)
typedef __attribute__((ext_vector_type(4))) float f32x4;    // MFMA C/D frag

__device__ __forceinline__ unsigned short bf16_rtne(float f) {
    unsigned int u = __float_as_uint(f);
    u += 0x7FFFu + ((u >> 16) & 1u);
    return (unsigned short)(u >> 16);
}
__device__ __forceinline__ float bf16_to_f(unsigned short h) {
    return __uint_as_float(((unsigned int)h) << 16);
}

// SESSION LEDGER (proven on this problem):
//  - R0 = 107us vq_main: bf16 3-split, h+m tables LDS-staged via frag-order map,
//    l streamed from L2 w/ 1-tile prefetch, 256x1024 @ (1024,4). FASTEST LOOP.
//  - R1/R2: reg cap < 128 spills the K-loop (+50-80MB HBM scratch). Never.
//  - R3/R4/R5 all ~210us despite disjoint structures; shared elements were the
//    f16 2-split loop AND __threadfence() in the fused finalize (perfectly
//    confounded). This kernel: R0 loop verbatim + fence-LESS fused finalize.
//    Fence is unnecessary: counts/loss/done_ctr are touched only by device-
//    scope atomics, and __syncthreads() already drains vmcnt per wave, so the
//    ticket-add is ordered after the counts-adds without any L2 WB/INV.

// 6 split-products per k-step: hh, hm, mh, hl, lh, mm (R5..R11 order — passed)
#define MFMA_STEP(AH, AM, AL, XH, XM, XL, ACC) \
    ACC = __builtin_amdgcn_mfma_f32_16x16x32_bf16(AH, XH, ACC, 0, 0, 0); \
    ACC = __builtin_amdgcn_mfma_f32_16x16x32_bf16(AH, XM, ACC, 0, 0, 0); \
    ACC = __builtin_amdgcn_mfma_f32_16x16x32_bf16(AM, XH, ACC, 0, 0, 0); \
    ACC = __builtin_amdgcn_mfma_f32_16x16x32_bf16(AH, XL, ACC, 0, 0, 0); \
    ACC = __builtin_amdgcn_mfma_f32_16x16x32_bf16(AL, XH, ACC, 0, 0, 0); \
    ACC = __builtin_amdgcn_mfma_f32_16x16x32_bf16(AM, XM, ACC, 0, 0, 0);

// ws layout: [0,2048) int counts | [2048,4096) float hnorms | [4096] loss |
//            [4160] done_ctr | [8192) ebh ushort[32768] | +64KB ebm | +64KB ebl
__global__ void vq_init(const float* __restrict__ emb, int* __restrict__ counts,
                        float* __restrict__ hnorms, float* __restrict__ loss_acc,
                        int* __restrict__ done_ctr,
                        unsigned short* __restrict__ ebh, unsigned short* __restrict__ ebm,
                        unsigned short* __restrict__ ebl) {
    const int k = blockIdx.x;
    const int c = threadIdx.x;
    float x = emb[k * DDIM + c];
    unsigned short h = bf16_rtne(x);
    float r1 = x - bf16_to_f(h);          // exact (Sterbenz)
    unsigned short m = bf16_rtne(r1);
    float r2 = r1 - bf16_to_f(m);         // exact
    unsigned short l = bf16_rtne(r2);
    ebh[k * DDIM + c] = h; ebm[k * DDIM + c] = m; ebl[k * DDIM + c] = l;
    float s = x * x;
#pragma unroll
    for (int off = 1; off <= 32; off <<= 1) s += __shfl_xor(s, off, 64);
    if (c == 0) {
        hnorms[k] = 0.5f * s;
        counts[k] = 0;
        if (k == 0) { *loss_acc = 0.f; *done_ctr = 0; }
    }
}

// One 1024-thread block per CU (256 blocks). h+m split tables (128 KB) + hnorms
// + hist in LDS; K-loop is BARRIER-FREE (16 waves free-run). Al fragments come
// from the L2-resident 64-KB global table with 1-tile prefetch. (1024,4): the
// only reg cap that never spilled. Body == R0 verbatim; only the finalize is new.
__global__ __launch_bounds__(1024, 4) void vq_main(
    const float* __restrict__ in, const float* __restrict__ emb,
    const unsigned short* __restrict__ ebh, const unsigned short* __restrict__ ebm,
    const unsigned short* __restrict__ ebl,
    const float* __restrict__ hnorms, int* __restrict__ counts,
    float* __restrict__ loss_acc, int* __restrict__ done_ctr,
    float* __restrict__ dout)
{
    __shared__ __align__(16) unsigned short ebh_l[KEMB * DDIM];  // 64 KB
    __shared__ __align__(16) unsigned short ebm_l[KEMB * DDIM];  // 64 KB
    __shared__ __align__(16) float hn_lds[KEMB];                 // 2 KB
    __shared__ int hist[KEMB];                                   // 2 KB
    __shared__ float part[8];
    __shared__ int lastflag;

    const int t    = threadIdx.x;         // 0..1023
    const int lane = t & 63;
    const int wv   = t >> 6;              // wave id 0..15
    const int quad = lane >> 4;
    const int col  = lane & 15;
    const int b    = blockIdx.x >> 3;                        // 8 blocks per image
    const int p0   = ((blockIdx.x & 7) << 9) | (wv << 5);    // first of this wave's 32 px
    const float* xb = in + b * BSTRIDE;

    if (t < KEMB) hist[t] = 0;
    if (t < 128) ((float4*)hn_lds)[t] = ((const float4*)hnorms)[t];

    // ---- Stage h,m tables into LDS in fragment order (R7-proven mapping).
#pragma unroll
    for (int i = 0; i < 4; ++i) {
        const int f  = t + i * 1024;
        const int ct = f >> 7;
        const int ks = (f >> 6) & 1;
        const int lf = f & 63;
        const int src = (ct * 16 + (lf & 15)) * DDIM + ks * 32 + (lf >> 4) * 8;
        const int dst = ct * 1024 + ks * 512 + lf * 8;
        *(bf16x8*)&ebh_l[dst] = *(const bf16x8*)(ebh + src);
        *(bf16x8*)&ebm_l[dst] = *(const bf16x8*)(ebm + src);
    }

    // ---- Build x B-fragments: B[n=col][k=quad*8+j], xf[split][ptile][kstep]
    bf16x8 xf[3][2][2];
#pragma unroll
    for (int tt = 0; tt < 2; ++tt) {
#pragma unroll
        for (int s = 0; s < 2; ++s) {
            const int pp = p0 + tt * 16 + col;
            const int c0 = s * 32 + quad * 8;
            bf16x8 vh, vm, vl;
#pragma unroll
            for (int j = 0; j < 8; ++j) {
                float x = xb[(c0 + j) * HW + pp];
                unsigned short h = bf16_rtne(x);
                float r1 = x - bf16_to_f(h);
                unsigned short m = bf16_rtne(r1);
                float r2 = r1 - bf16_to_f(m);
                unsigned short l = bf16_rtne(r2);
                vh[j] = (short)h; vm[j] = (short)m; vl[j] = (short)l;
            }
            xf[0][tt][s] = vh; xf[1][tt][s] = vm; xf[2][tt][s] = vl;
        }
    }

    __syncthreads();   // staging done; K-loop below is barrier-free

    // ---- K-loop over 32 code tiles
    const int arow = col * DDIM + quad * 8;   // Al per-lane offset within a tile
    float v1[2], v2[2]; int k1[2], k2[2];
#pragma unroll
    for (int tt = 0; tt < 2; ++tt) {
        v1[tt] = 3.402823466e38f; v2[tt] = 3.402823466e38f; k1[tt] = 0; k2[tt] = 0;
    }

    bf16x8 Al0 = *(const bf16x8*)(ebl + arow);
    bf16x8 Al1 = *(const bf16x8*)(ebl + arow + 32);

    for (int ct = 0; ct < 32; ++ct) {
        // Prefetch next tile's Al fragments (drains under this tile's MFMAs)
        bf16x8 Al0n, Al1n;
        if (ct < 31) {
            const int sb = (ct + 1) * 1024 + arow;
            Al0n = *(const bf16x8*)(ebl + sb);
            Al1n = *(const bf16x8*)(ebl + sb + 32);
        }

        const int base = ct * 1024 + lane * 8;
        const bf16x8 Ah0 = *(const bf16x8*)&ebh_l[base];
        const bf16x8 Ah1 = *(const bf16x8*)&ebh_l[base + 512];
        const bf16x8 Am0 = *(const bf16x8*)&ebm_l[base];
        const bf16x8 Am1 = *(const bf16x8*)&ebm_l[base + 512];

        f32x4 acc0 = (f32x4){0.f, 0.f, 0.f, 0.f};
        f32x4 acc1 = (f32x4){0.f, 0.f, 0.f, 0.f};
        MFMA_STEP(Ah0, Am0, Al0, xf[0][0][0], xf[1][0][0], xf[2][0][0], acc0)
        MFMA_STEP(Ah1, Am1, Al1, xf[0][0][1], xf[1][0][1], xf[2][0][1], acc0)
        MFMA_STEP(Ah0, Am0, Al0, xf[0][1][0], xf[1][1][0], xf[2][1][0], acc1)
        MFMA_STEP(Ah1, Am1, Al1, xf[0][1][1], xf[1][1][1], xf[2][1][1], acc1)

        const f32x4 hn = *(const f32x4*)&hn_lds[ct * 16 + quad * 4];
#pragma unroll
        for (int r = 0; r < 4; ++r) {
            const int kk = ct * 16 + quad * 4 + r;
            float sc = hn[r] - acc0[r];
            if (sc < v1[0]) { v2[0] = v1[0]; k2[0] = k1[0]; v1[0] = sc; k1[0] = kk; }
            else if (sc < v2[0]) { v2[0] = sc; k2[0] = kk; }
            sc = hn[r] - acc1[r];
            if (sc < v1[1]) { v2[1] = v1[1]; k2[1] = k1[1]; v1[1] = sc; k1[1] = kk; }
            else if (sc < v2[1]) { v2[1] = sc; k2[1] = kk; }
        }

        Al0 = Al0n; Al1 = Al1n;
    }

    // Cross-quad top-2 merge (lanes l, l^16, l^32 share pixel-col) — R6 verbatim
#pragma unroll
    for (int tt = 0; tt < 2; ++tt) {
#pragma unroll
        for (int off = 16; off <= 32; off <<= 1) {
            float w1 = __shfl_xor(v1[tt], off, 64); int j1 = __shfl_xor(k1[tt], off, 64);
            float w2 = __shfl_xor(v2[tt], off, 64); int j2 = __shfl_xor(k2[tt], off, 64);
            bool aF = (v1[tt] < w1) || (v1[tt] == w1 && k1[tt] < j1);
            float t1 = aF ? v1[tt] : w1;  int u1 = aF ? k1[tt] : j1;
            float tl = aF ? w1 : v1[tt];  int ul = aF ? j1 : k1[tt];      // loser of firsts
            bool bS = (v2[tt] < w2) || (v2[tt] == w2 && k2[tt] < j2);
            float tc = bS ? v2[tt] : w2;  int uc = bS ? k2[tt] : j2;      // better of seconds
            bool lS = (tl < tc) || (tl == tc && ul < uc);
            v1[tt] = t1; k1[tt] = u1;
            v2[tt] = lS ? tl : tc; k2[tt] = lS ? ul : uc;
        }
    }

    // Pixel q = lane&31; lanes l and l+32 handle the same pixel (tt = (l>>4)&1).
    const int q    = lane & 31;
    const int pp   = p0 + q;
    const int tsel = (lane >> 4) & 1;
    const int kA = tsel ? k1[1] : k1[0];
    const int kB = tsel ? k2[1] : k2[0];

    // Exact fp32 rescore, split: lanes<32 score kA, lanes>=32 score kB.
    // Streaming x loads (no x[64] array!) — ops and order bitwise == R11 chain.
    const int kMine = (lane < 32) ? kA : kB;
    const float4* eM = (const float4*)(emb + kMine * DDIM);
    float a0 = hn_lds[kMine], a1 = 0.f, a2 = 0.f, a3 = 0.f;
#pragma unroll
    for (int i = 0; i < 16; ++i) {
        float4 ea = eM[i];
        const int c = i * 4;
        float x0 = xb[(c + 0) * HW + pp];
        float x1 = xb[(c + 1) * HW + pp];
        float x2 = xb[(c + 2) * HW + pp];
        float x3 = xb[(c + 3) * HW + pp];
        a0 = fmaf(-x0, ea.x, a0);
        a1 = fmaf(-x1, ea.y, a1);
        a2 = fmaf(-x2, ea.z, a2);
        a3 = fmaf(-x3, ea.w, a3);
    }
    const float dMine = (a0 + a1) + (a2 + a3);
    const float dOth  = __shfl_xor(dMine, 32, 64);
    const float dA = (lane < 32) ? dMine : dOth;
    const float dB = (lane < 32) ? dOth  : dMine;
    const int myk = (dB < dA || (dB == dA && kB < kA)) ? kB : kA;

    float lsum = 0.f;
    if (lane < 32) {
        dout[IDX_OFF + b * HW + pp] = (float)myk;
        atomicAdd(&hist[myk], 1);
        const float4* qrow = (const float4*)(emb + myk * DDIM);
        float* ob = dout + OUT_OFF + b * BSTRIDE;
#pragma unroll
        for (int i = 0; i < 16; ++i) {
            float4 qv = qrow[i];
            const int c = i * 4;
            float x0 = xb[(c + 0) * HW + pp];   // L1-warm reload (just read above)
            float x1 = xb[(c + 1) * HW + pp];
            float x2 = xb[(c + 2) * HW + pp];
            float x3 = xb[(c + 3) * HW + pp];
            float d0 = qv.x - x0;
            float d1 = qv.y - x1;
            float d2 = qv.z - x2;
            float d3 = qv.w - x3;
            lsum += d0 * d0 + d1 * d1 + d2 * d2 + d3 * d3;
            ob[(c + 0) * HW + pp] = x0 + d0;    // reference rounding: x + (q - x)
            ob[(c + 1) * HW + pp] = x1 + d1;
            ob[(c + 2) * HW + pp] = x2 + d2;
            ob[(c + 3) * HW + pp] = x3 + d3;
        }
    }
    for (int off = 32; off > 0; off >>= 1) lsum += __shfl_down(lsum, off, 64);
    if (lane == 0) atomicAdd(loss_acc, lsum);

    __syncthreads();
    if (t < KEMB) {
        int v = hist[t];
        if (v) atomicAdd(&counts[t], v);
    }

    // ---- Fused finalize, fence-LESS: __syncthreads() drains each wave's
    // vmcnt (compiler-emitted full waitcnt before s_barrier), so every counts/
    // loss atomic of this block has committed at the device coherence point
    // before t==0 issues the ticket. All cross-block state is atomic-only —
    // no __threadfence (no buffer_wbl2/inv storm) needed.
    __syncthreads();
    if (t == 0) lastflag = (atomicAdd(done_ctr, 1) == 255) ? 1 : 0;
    __syncthreads();
    if (lastflag) {
        if (t < KEMB) {
            int cnt = atomicAdd(&counts[t], 0);   // device-coherent read
            float pa = (float)cnt / (float)NPIX;
            float v = pa * logf(pa + 1e-10f);
#pragma unroll
            for (int off = 1; off <= 32; off <<= 1) v += __shfl_xor(v, off, 64);
            if ((t & 63) == 0) part[t >> 6] = v;
        }
        __syncthreads();
        if (t == 0) {
            float s = 0.f;
#pragma unroll
            for (int i = 0; i < 8; ++i) s += part[i];
            dout[PERP_OFF] = expf(-s);
            dout[0] = 0.25f * atomicAdd(loss_acc, 0.0f) / 8388608.0f;
        }
    }
}

extern "C" void kernel_launch(void* const* d_in, const int* in_sizes, int n_in,
                              void* d_out, int out_size, void* d_ws, size_t ws_size,
                              hipStream_t stream) {
    const float* in  = (const float*)d_in[0];   // 8388608 elems
    const float* emb = (const float*)d_in[1];   // 32768 elems
    float* dout = (float*)d_out;
    int*   counts   = (int*)d_ws;
    float* hnorms   = (float*)((char*)d_ws + 2048);
    float* loss_acc = (float*)((char*)d_ws + 4096);
    int*   done_ctr = (int*)((char*)d_ws + 4160);
    unsigned short* ebh = (unsigned short*)((char*)d_ws + 8192);
    unsigned short* ebm = ebh + KEMB * DDIM;
    unsigned short* ebl = ebm + KEMB * DDIM;

    vq_init<<<512, 64, 0, stream>>>(emb, counts, hnorms, loss_acc, done_ctr, ebh, ebm, ebl);
    vq_main<<<256, 1024, 0, stream>>>(in, emb, ebh, ebm, ebl, hnorms, counts, loss_acc, done_ctr, dout);
}

// Round 8
// 162.603 us; speedup vs baseline: 1.7493x; 1.0777x over previous
//
#include <hip/hip_runtime.h>
#include <hip/hip_fp16.h>
#include <math.h>

// Problem constants
#define NPIX   131072      // B*H*W = 32*64*64
#define KEMB   512
#define DDIM   64
#define HW     4096        // H*W
#define BSTRIDE 262144     // C*H*W

// d_out flat layout (float32): [loss(1) | out(8388608) | perplexity(1) | indices(131072)]
#define OUT_OFF  1
#define PERP_OFF 8388609
#define IDX_OFF  8388610

typedef __attribute__((ext_vector_type(8))) _Float16 f16x8;    // MFMA A/B frag (4 VGPRs)
typedef __attribute__((ext_vector_type(4))) float f32x4;       // MFMA C/D frag

// SESSION LEDGER (proven on this problem):
//  - R0/R6 = 107us vq_main: bf16 3-split loop, (1024,4), 1 block/CU, 16 waves.
//  - R6 proved: fence-LESS fused finalize is clean (total 175.2, no pathology).
//    Also proved: launch-count doesn't matter — ~64us of total is fixed harness
//    overhead; only vq_main time is addressable.
//  - R1/R2: reg cap < 128 spills the K-loop (+50-80MB HBM scratch). Never.
//  - R3: in-K-loop global fragment streams serialize on load latency. Never.
//  - R4: in-block table build = conflicted u16 scatters. Never.
//  - Occupancy is QUANTIZED: 65..128 regs -> 4 waves/SIMD = 16 waves/CU. The
//    only other step is <=64 regs (spills here). 16 waves/CU is the ceiling.
//  - R7 never ran (container failure). THIS KERNEL = R7 resubmitted: resolves
//    the R3/R4/R5 confound {f16 2-split ? __threadfence}: R5's f16 2-split
//    loop (absmax 0, MFMA pipe time exactly halved to 10.2us) in R6's
//    fence-less shell. If fence was the curse -> vq_main ~97us.
//
// 2-split f16 scheme (absmax 0 in R2/R3/R4/R5): x = h + l/2048 + r,
// |r|<=2^-21|x|. l pre-scaled by 2^11 (exact pow2) stays in f16 normal range.
// Products kept: hh + (h*l'+l'*h)/2048; dropped terms ~1e-4 absolute, and the
// exact fp32 top-2 rescore (R0-verbatim) decides the final index.

// ws layout: [0,2048) int counts | [2048,4096) float hnorms | [4096] loss |
//            [4160] done_ctr | [8192,73728) eh_t (f16 high, frag-linear, 64KB) |
//            [73728,139264) el_t (f16 low pre-scaled by 2^11, frag-linear, 64KB)
// frag-linear: idx = ct*1024 + ks*512 + (quad*16+col)*8 + j  (R5-proven), so
// vq_main stages both tables with straight linear 16B/lane copies.
__global__ void vq_init(const float* __restrict__ emb, int* __restrict__ counts,
                        float* __restrict__ hnorms, float* __restrict__ loss_acc,
                        int* __restrict__ done_ctr,
                        unsigned short* __restrict__ eh_t,
                        unsigned short* __restrict__ el_t) {
    const int k = blockIdx.x;             // code
    const int c = threadIdx.x;            // channel
    const int ct = k >> 4, cl = k & 15;
    const int ks = c >> 5, qd = (c >> 3) & 3, j = c & 7;
    float x = emb[k * DDIM + c];
    _Float16 h = (_Float16)x;             // v_cvt_f16_f32, RTNE
    float r1 = x - (float)h;              // exact (Sterbenz)
    _Float16 l = (_Float16)(r1 * 2048.0f);
    const int dst = ct * 1024 + ks * 512 + (qd * 16 + cl) * 8 + j;
    ((_Float16*)eh_t)[dst] = h;
    ((_Float16*)el_t)[dst] = l;
    float s = x * x;
#pragma unroll
    for (int off = 1; off <= 32; off <<= 1) s += __shfl_xor(s, off, 64);
    if (c == 0) {
        hnorms[k] = 0.5f * s;
        counts[k] = 0;
        if (k == 0) { *loss_acc = 0.f; *done_ctr = 0; }
    }
}

// 256 blocks x 1024 threads, 1 block/CU, 16 waves (proven shape). LDS 132KB:
// both f16 tables resident -> K-loop is pure LDS + 12 MFMA/tile, barrier-free.
__global__ __launch_bounds__(1024, 4) void vq_main(
    const float* __restrict__ in, const float* __restrict__ emb,
    const unsigned short* __restrict__ eh_t, const unsigned short* __restrict__ el_t,
    const float* __restrict__ hnorms, int* __restrict__ counts,
    float* __restrict__ loss_acc, int* __restrict__ done_ctr,
    float* __restrict__ dout)
{
    __shared__ __align__(16) _Float16 eh_l[KEMB * DDIM];   // 64 KB
    __shared__ __align__(16) _Float16 el_l[KEMB * DDIM];   // 64 KB
    __shared__ __align__(16) float hn_lds[KEMB];           // 2 KB
    __shared__ int hist[KEMB];                             // 2 KB
    __shared__ float part[8];
    __shared__ int lastflag;

    const int t    = threadIdx.x;         // 0..1023
    const int lane = t & 63;
    const int wv   = t >> 6;              // wave id 0..15
    const int quad = lane >> 4;
    const int col  = lane & 15;
    const int b    = blockIdx.x >> 3;                        // 8 blocks per image
    const int p0   = ((blockIdx.x & 7) << 9) | (wv << 5);    // first of this wave's 32 px
    const float* xb = in + b * BSTRIDE;

    if (t < KEMB) hist[t] = 0;
    if (t < 128) ((float4*)hn_lds)[t] = ((const float4*)hnorms)[t];

    // ---- Stage both tables into LDS: linear 16B/lane copies (R5-proven,
    // conflict-free: byte addr = 16*t, same pattern as the K-loop reads).
#pragma unroll
    for (int i = 0; i < 4; ++i) {
        const int f = (t + i * 1024) * 8;
        *(f16x8*)&eh_l[f] = *(const f16x8*)((const _Float16*)eh_t + f);
        *(f16x8*)&el_l[f] = *(const f16x8*)((const _Float16*)el_t + f);
    }

    // ---- Build x B-fragments: B[n=col][k=quad*8+j], xh/xl[ptile][kstep]
    f16x8 xh[2][2], xl[2][2];
#pragma unroll
    for (int tt = 0; tt < 2; ++tt) {
#pragma unroll
        for (int s = 0; s < 2; ++s) {
            const int ppb = p0 + tt * 16 + col;
            const int c0  = s * 32 + quad * 8;
            f16x8 vh, vl;
#pragma unroll
            for (int j = 0; j < 8; ++j) {
                float x = xb[(c0 + j) * HW + ppb];
                _Float16 h = (_Float16)x;
                float r1 = x - (float)h;
                vh[j] = h;
                vl[j] = (_Float16)(r1 * 2048.0f);
            }
            xh[tt][s] = vh; xl[tt][s] = vl;
        }
    }

    __syncthreads();   // tables + hn + hist ready; K-loop below is barrier-free

    // ---- K-loop over 32 code tiles — pure LDS reads + 12 MFMA per tile
    // (body verbatim == R5's passing kernel)
    float v1[2], v2[2]; int k1[2], k2[2];
#pragma unroll
    for (int tt = 0; tt < 2; ++tt) {
        v1[tt] = 3.402823466e38f; v2[tt] = 3.402823466e38f; k1[tt] = 0; k2[tt] = 0;
    }

    for (int ct = 0; ct < 32; ++ct) {
        const int base = ct * 1024 + lane * 8;
        const f16x8 Ah0 = *(const f16x8*)&eh_l[base];
        const f16x8 Ah1 = *(const f16x8*)&eh_l[base + 512];
        const f16x8 Al0 = *(const f16x8*)&el_l[base];
        const f16x8 Al1 = *(const f16x8*)&el_l[base + 512];

        f32x4 a0h = (f32x4){0.f, 0.f, 0.f, 0.f};
        f32x4 a0l = (f32x4){0.f, 0.f, 0.f, 0.f};
        f32x4 a1h = (f32x4){0.f, 0.f, 0.f, 0.f};
        f32x4 a1l = (f32x4){0.f, 0.f, 0.f, 0.f};
        a0h = __builtin_amdgcn_mfma_f32_16x16x32_f16(Ah0, xh[0][0], a0h, 0, 0, 0);
        a0l = __builtin_amdgcn_mfma_f32_16x16x32_f16(Ah0, xl[0][0], a0l, 0, 0, 0);
        a0l = __builtin_amdgcn_mfma_f32_16x16x32_f16(Al0, xh[0][0], a0l, 0, 0, 0);
        a1h = __builtin_amdgcn_mfma_f32_16x16x32_f16(Ah0, xh[1][0], a1h, 0, 0, 0);
        a1l = __builtin_amdgcn_mfma_f32_16x16x32_f16(Ah0, xl[1][0], a1l, 0, 0, 0);
        a1l = __builtin_amdgcn_mfma_f32_16x16x32_f16(Al0, xh[1][0], a1l, 0, 0, 0);
        a0h = __builtin_amdgcn_mfma_f32_16x16x32_f16(Ah1, xh[0][1], a0h, 0, 0, 0);
        a0l = __builtin_amdgcn_mfma_f32_16x16x32_f16(Ah1, xl[0][1], a0l, 0, 0, 0);
        a0l = __builtin_amdgcn_mfma_f32_16x16x32_f16(Al1, xh[0][1], a0l, 0, 0, 0);
        a1h = __builtin_amdgcn_mfma_f32_16x16x32_f16(Ah1, xh[1][1], a1h, 0, 0, 0);
        a1l = __builtin_amdgcn_mfma_f32_16x16x32_f16(Ah1, xl[1][1], a1l, 0, 0, 0);
        a1l = __builtin_amdgcn_mfma_f32_16x16x32_f16(Al1, xh[1][1], a1l, 0, 0, 0);

        const f32x4 hn = *(const f32x4*)&hn_lds[ct * 16 + quad * 4];
#pragma unroll
        for (int r = 0; r < 4; ++r) {
            const int kk = ct * 16 + quad * 4 + r;
            float sc = hn[r] - (a0h[r] + a0l[r] * 4.8828125e-4f);  // + acc_l/2048
            if (sc < v1[0]) { v2[0] = v1[0]; k2[0] = k1[0]; v1[0] = sc; k1[0] = kk; }
            else if (sc < v2[0]) { v2[0] = sc; k2[0] = kk; }
            sc = hn[r] - (a1h[r] + a1l[r] * 4.8828125e-4f);
            if (sc < v1[1]) { v2[1] = v1[1]; k2[1] = k1[1]; v1[1] = sc; k1[1] = kk; }
            else if (sc < v2[1]) { v2[1] = sc; k2[1] = kk; }
        }
    }

    // Cross-quad top-2 merge (lanes l, l^16, l^32 share pixel-col) — R0 verbatim
#pragma unroll
    for (int tt = 0; tt < 2; ++tt) {
#pragma unroll
        for (int off = 16; off <= 32; off <<= 1) {
            float w1 = __shfl_xor(v1[tt], off, 64); int j1 = __shfl_xor(k1[tt], off, 64);
            float w2 = __shfl_xor(v2[tt], off, 64); int j2 = __shfl_xor(k2[tt], off, 64);
            bool aF = (v1[tt] < w1) || (v1[tt] == w1 && k1[tt] < j1);
            float t1 = aF ? v1[tt] : w1;  int u1 = aF ? k1[tt] : j1;
            float tl = aF ? w1 : v1[tt];  int ul = aF ? j1 : k1[tt];      // loser of firsts
            bool bS = (v2[tt] < w2) || (v2[tt] == w2 && k2[tt] < j2);
            float tc = bS ? v2[tt] : w2;  int uc = bS ? k2[tt] : j2;      // better of seconds
            bool lS = (tl < tc) || (tl == tc && ul < uc);
            v1[tt] = t1; k1[tt] = u1;
            v2[tt] = lS ? tl : tc; k2[tt] = lS ? ul : uc;
        }
    }

    // Pixel q = lane&31; lanes l and l+32 handle the same pixel (tt = (l>>4)&1).
    const int q    = lane & 31;
    const int pp   = p0 + q;
    const int tsel = (lane >> 4) & 1;
    const int kA = tsel ? k1[1] : k1[0];
    const int kB = tsel ? k2[1] : k2[0];

    // Exact fp32 rescore, split: lanes<32 score kA, lanes>=32 score kB.
    // Streaming x loads — ops and order bitwise == the passing kernels.
    const int kMine = (lane < 32) ? kA : kB;
    const float4* eM = (const float4*)(emb + kMine * DDIM);
    float a0 = hn_lds[kMine], a1 = 0.f, a2 = 0.f, a3 = 0.f;
#pragma unroll
    for (int i = 0; i < 16; ++i) {
        float4 ea = eM[i];
        const int c = i * 4;
        float x0 = xb[(c + 0) * HW + pp];
        float x1 = xb[(c + 1) * HW + pp];
        float x2 = xb[(c + 2) * HW + pp];
        float x3 = xb[(c + 3) * HW + pp];
        a0 = fmaf(-x0, ea.x, a0);
        a1 = fmaf(-x1, ea.y, a1);
        a2 = fmaf(-x2, ea.z, a2);
        a3 = fmaf(-x3, ea.w, a3);
    }
    const float dMine = (a0 + a1) + (a2 + a3);
    const float dOth  = __shfl_xor(dMine, 32, 64);
    const float dA = (lane < 32) ? dMine : dOth;
    const float dB = (lane < 32) ? dOth  : dMine;
    const int myk = (dB < dA || (dB == dA && kB < kA)) ? kB : kA;

    float lsum = 0.f;
    if (lane < 32) {
        dout[IDX_OFF + b * HW + pp] = (float)myk;
        atomicAdd(&hist[myk], 1);
        const float4* qrow = (const float4*)(emb + myk * DDIM);
        float* ob = dout + OUT_OFF + b * BSTRIDE;
#pragma unroll
        for (int i = 0; i < 16; ++i) {
            float4 qv = qrow[i];
            const int c = i * 4;
            float x0 = xb[(c + 0) * HW + pp];   // L1-warm reload (just read above)
            float x1 = xb[(c + 1) * HW + pp];
            float x2 = xb[(c + 2) * HW + pp];
            float x3 = xb[(c + 3) * HW + pp];
            float d0 = qv.x - x0;
            float d1 = qv.y - x1;
            float d2 = qv.z - x2;
            float d3 = qv.w - x3;
            lsum += d0 * d0 + d1 * d1 + d2 * d2 + d3 * d3;
            ob[(c + 0) * HW + pp] = x0 + d0;    // reference rounding: x + (q - x)
            ob[(c + 1) * HW + pp] = x1 + d1;
            ob[(c + 2) * HW + pp] = x2 + d2;
            ob[(c + 3) * HW + pp] = x3 + d3;
        }
    }
    for (int off = 32; off > 0; off >>= 1) lsum += __shfl_down(lsum, off, 64);
    if (lane == 0) atomicAdd(loss_acc, lsum);

    __syncthreads();
    if (t < KEMB) {
        int v = hist[t];
        if (v) atomicAdd(&counts[t], v);
    }

    // ---- Fused finalize, fence-LESS (R6-proven): __syncthreads() drains each
    // wave's vmcnt before s_barrier, so this block's counts/loss atomics have
    // committed at the device coherence point before t==0 issues the ticket.
    // All cross-block state is atomic-only — no __threadfence (no L2 WB/INV).
    __syncthreads();
    if (t == 0) lastflag = (atomicAdd(done_ctr, 1) == 255) ? 1 : 0;
    __syncthreads();
    if (lastflag) {
        if (t < KEMB) {
            int cnt = atomicAdd(&counts[t], 0);   // device-coherent read
            float pa = (float)cnt / (float)NPIX;
            float v = pa * logf(pa + 1e-10f);
#pragma unroll
            for (int off = 1; off <= 32; off <<= 1) v += __shfl_xor(v, off, 64);
            if ((t & 63) == 0) part[t >> 6] = v;
        }
        __syncthreads();
        if (t == 0) {
            float s = 0.f;
#pragma unroll
            for (int i = 0; i < 8; ++i) s += part[i];
            dout[PERP_OFF] = expf(-s);
            dout[0] = 0.25f * atomicAdd(loss_acc, 0.0f) / 8388608.0f;
        }
    }
}

extern "C" void kernel_launch(void* const* d_in, const int* in_sizes, int n_in,
                              void* d_out, int out_size, void* d_ws, size_t ws_size,
                              hipStream_t stream) {
    const float* in  = (const float*)d_in[0];   // 8388608 elems
    const float* emb = (const float*)d_in[1];   // 32768 elems
    float* dout = (float*)d_out;
    int*   counts   = (int*)d_ws;
    float* hnorms   = (float*)((char*)d_ws + 2048);
    float* loss_acc = (float*)((char*)d_ws + 4096);
    int*   done_ctr = (int*)((char*)d_ws + 4160);
    unsigned short* eh_t = (unsigned short*)((char*)d_ws + 8192);
    unsigned short* el_t = eh_t + KEMB * DDIM;   // 64 KB scaled-l table

    vq_init<<<512, 64, 0, stream>>>(emb, counts, hnorms, loss_acc, done_ctr, eh_t, el_t);
    vq_main<<<256, 1024, 0, stream>>>(in, emb, eh_t, el_t, hnorms, counts, loss_acc, done_ctr, dout);
}

// Round 9
// 153.501 us; speedup vs baseline: 1.8530x; 1.0593x over previous
//
#include <hip/hip_runtime.h>
#include <hip/hip_fp16.h>
#include <math.h>

// Problem constants
#define NPIX   131072      // B*H*W = 32*64*64
#define KEMB   512
#define DDIM   64
#define HW     4096        // H*W
#define BSTRIDE 262144     // C*H*W

// d_out flat layout (float32): [loss(1) | out(8388608) | perplexity(1) | indices(131072)]
#define OUT_OFF  1
#define PERP_OFF 8388609
#define IDX_OFF  8388610

typedef __attribute__((ext_vector_type(8))) _Float16 f16x8;    // MFMA A/B frag (4 VGPRs)
typedef __attribute__((ext_vector_type(4))) float f32x4;       // MFMA C/D frag

// SESSION LEDGER (proven on this problem):
//  - R8 = 95us vq_main (total 162.6, best): f16 2-split K-loop, both tables
//    LDS-resident, (1024,4), 1 block/CU, 16 waves, fence-LESS ticket finalize.
//  - R6-vs-R8 A/B proved: __threadfence() was the R3/R4/R5 ~2x curse (L2
//    WB/INV storm). NEVER use __threadfence; atomics + __syncthreads suffice.
//  - R1/R2: reg cap < 128 spills the K-loop (+50-80MB HBM scratch). Never.
//  - R3: in-K-loop global fragment streams serialize on load latency. Never.
//  - R4: in-block table build = conflicted u16 scatters. Never.
//  - Occupancy QUANTIZED: 65..128 regs -> 16 waves/CU; <=64 spills. 16 is max.
//  - R9 (this): +K-loop LDS prefetch pipeline, +med3/min top-2 update
//    (selection-equivalent, fewer VALU), +x-build moved after the barrier.
//    Distance values / candidate order / tie-breaks / loss chain unchanged.
//
// 2-split f16 scheme (absmax 0 in R2..R8): x = h + l/2048 + r, |r|<=2^-21|x|.
// l pre-scaled by 2^11 (exact pow2) stays in f16 normal range. Products kept:
// hh + (h*l'+l'*h)/2048; dropped terms ~1e-4 absolute, and the exact fp32
// top-2 rescore decides the final index.

// ws layout: [0,2048) int counts | [2048,4096) float hnorms | [4096] loss |
//            [4160] done_ctr | [8192,73728) eh_t (f16 high, frag-linear, 64KB) |
//            [73728,139264) el_t (f16 low pre-scaled by 2^11, frag-linear, 64KB)
// frag-linear: idx = ct*1024 + ks*512 + (quad*16+col)*8 + j  (R5-proven), so
// vq_main stages both tables with straight linear 16B/lane copies.
__global__ void vq_init(const float* __restrict__ emb, int* __restrict__ counts,
                        float* __restrict__ hnorms, float* __restrict__ loss_acc,
                        int* __restrict__ done_ctr,
                        unsigned short* __restrict__ eh_t,
                        unsigned short* __restrict__ el_t) {
    const int k = blockIdx.x;             // code
    const int c = threadIdx.x;            // channel
    const int ct = k >> 4, cl = k & 15;
    const int ks = c >> 5, qd = (c >> 3) & 3, j = c & 7;
    float x = emb[k * DDIM + c];
    _Float16 h = (_Float16)x;             // v_cvt_f16_f32, RTNE
    float r1 = x - (float)h;              // exact (Sterbenz)
    _Float16 l = (_Float16)(r1 * 2048.0f);
    const int dst = ct * 1024 + ks * 512 + (qd * 16 + cl) * 8 + j;
    ((_Float16*)eh_t)[dst] = h;
    ((_Float16*)el_t)[dst] = l;
    float s = x * x;
#pragma unroll
    for (int off = 1; off <= 32; off <<= 1) s += __shfl_xor(s, off, 64);
    if (c == 0) {
        hnorms[k] = 0.5f * s;
        counts[k] = 0;
        if (k == 0) { *loss_acc = 0.f; *done_ctr = 0; }
    }
}

// 256 blocks x 1024 threads, 1 block/CU, 16 waves (proven shape). LDS 132KB:
// both f16 tables resident -> K-loop is pure LDS + 12 MFMA/tile, barrier-free,
// software-pipelined (next tile's fragments prefetched under the select chain).
__global__ __launch_bounds__(1024, 4) void vq_main(
    const float* __restrict__ in, const float* __restrict__ emb,
    const unsigned short* __restrict__ eh_t, const unsigned short* __restrict__ el_t,
    const float* __restrict__ hnorms, int* __restrict__ counts,
    float* __restrict__ loss_acc, int* __restrict__ done_ctr,
    float* __restrict__ dout)
{
    __shared__ __align__(16) _Float16 eh_l[KEMB * DDIM];   // 64 KB
    __shared__ __align__(16) _Float16 el_l[KEMB * DDIM];   // 64 KB
    __shared__ __align__(16) float hn_lds[KEMB];           // 2 KB
    __shared__ int hist[KEMB];                             // 2 KB
    __shared__ float part[8];
    __shared__ int lastflag;

    const int t    = threadIdx.x;         // 0..1023
    const int lane = t & 63;
    const int wv   = t >> 6;              // wave id 0..15
    const int quad = lane >> 4;
    const int col  = lane & 15;
    const int b    = blockIdx.x >> 3;                        // 8 blocks per image
    const int p0   = ((blockIdx.x & 7) << 9) | (wv << 5);    // first of this wave's 32 px
    const float* xb = in + b * BSTRIDE;

    if (t < KEMB) hist[t] = 0;
    if (t < 128) ((float4*)hn_lds)[t] = ((const float4*)hnorms)[t];

    // ---- Stage both tables into LDS: linear 16B/lane copies (R5-proven,
    // conflict-free: byte addr = 16*t, same pattern as the K-loop reads).
#pragma unroll
    for (int i = 0; i < 4; ++i) {
        const int f = (t + i * 1024) * 8;
        *(f16x8*)&eh_l[f] = *(const f16x8*)((const _Float16*)eh_t + f);
        *(f16x8*)&el_l[f] = *(const f16x8*)((const _Float16*)el_t + f);
    }

    __syncthreads();   // tables + hn + hist ready

    // ---- Build x B-fragments AFTER the barrier: per-wave private (registers
    // only), so no block-wide wait on the slowest wave's 32 HBM loads; each
    // wave's build overlaps other waves' K-loop ramp.
    f16x8 xh[2][2], xl[2][2];
#pragma unroll
    for (int tt = 0; tt < 2; ++tt) {
#pragma unroll
        for (int s = 0; s < 2; ++s) {
            const int ppb = p0 + tt * 16 + col;
            const int c0  = s * 32 + quad * 8;
            f16x8 vh, vl;
#pragma unroll
            for (int j = 0; j < 8; ++j) {
                float x = xb[(c0 + j) * HW + ppb];
                _Float16 h = (_Float16)x;
                float r1 = x - (float)h;
                vh[j] = h;
                vl[j] = (_Float16)(r1 * 2048.0f);
            }
            xh[tt][s] = vh; xl[tt][s] = vl;
        }
    }

    // ---- K-loop over 32 code tiles — pure LDS + 12 MFMA per tile, barrier-
    // free, software-pipelined. Distance arithmetic bitwise == R8.
    float v1[2], v2[2]; int k1[2], k2[2];
#pragma unroll
    for (int tt = 0; tt < 2; ++tt) {
        v1[tt] = 3.402823466e38f; v2[tt] = 3.402823466e38f; k1[tt] = 0; k2[tt] = 0;
    }

    // Prologue: tile 0 fragments
    f16x8 Ah0 = *(const f16x8*)&eh_l[lane * 8];
    f16x8 Ah1 = *(const f16x8*)&eh_l[lane * 8 + 512];
    f16x8 Al0 = *(const f16x8*)&el_l[lane * 8];
    f16x8 Al1 = *(const f16x8*)&el_l[lane * 8 + 512];

    for (int ct = 0; ct < 32; ++ct) {
        f32x4 a0h = (f32x4){0.f, 0.f, 0.f, 0.f};
        f32x4 a0l = (f32x4){0.f, 0.f, 0.f, 0.f};
        f32x4 a1h = (f32x4){0.f, 0.f, 0.f, 0.f};
        f32x4 a1l = (f32x4){0.f, 0.f, 0.f, 0.f};
        a0h = __builtin_amdgcn_mfma_f32_16x16x32_f16(Ah0, xh[0][0], a0h, 0, 0, 0);
        a0l = __builtin_amdgcn_mfma_f32_16x16x32_f16(Ah0, xl[0][0], a0l, 0, 0, 0);
        a0l = __builtin_amdgcn_mfma_f32_16x16x32_f16(Al0, xh[0][0], a0l, 0, 0, 0);
        a1h = __builtin_amdgcn_mfma_f32_16x16x32_f16(Ah0, xh[1][0], a1h, 0, 0, 0);
        a1l = __builtin_amdgcn_mfma_f32_16x16x32_f16(Ah0, xl[1][0], a1l, 0, 0, 0);
        a1l = __builtin_amdgcn_mfma_f32_16x16x32_f16(Al0, xh[1][0], a1l, 0, 0, 0);
        a0h = __builtin_amdgcn_mfma_f32_16x16x32_f16(Ah1, xh[0][1], a0h, 0, 0, 0);
        a0l = __builtin_amdgcn_mfma_f32_16x16x32_f16(Ah1, xl[0][1], a0l, 0, 0, 0);
        a0l = __builtin_amdgcn_mfma_f32_16x16x32_f16(Al1, xh[0][1], a0l, 0, 0, 0);
        a1h = __builtin_amdgcn_mfma_f32_16x16x32_f16(Ah1, xh[1][1], a1h, 0, 0, 0);
        a1l = __builtin_amdgcn_mfma_f32_16x16x32_f16(Ah1, xl[1][1], a1l, 0, 0, 0);
        a1l = __builtin_amdgcn_mfma_f32_16x16x32_f16(Al1, xh[1][1], a1l, 0, 0, 0);

        // Prefetch next tile's fragments ((ct+1)&31 wraps harmlessly at 31);
        // the ds_reads drain under the select chain below.
        const int nbase = (((ct + 1) & 31) * 1024) + lane * 8;
        const f16x8 nAh0 = *(const f16x8*)&eh_l[nbase];
        const f16x8 nAh1 = *(const f16x8*)&eh_l[nbase + 512];
        const f16x8 nAl0 = *(const f16x8*)&el_l[nbase];
        const f16x8 nAl1 = *(const f16x8*)&el_l[nbase + 512];

        const f32x4 hn = *(const f32x4*)&hn_lds[ct * 16 + quad * 4];
#pragma unroll
        for (int r = 0; r < 4; ++r) {
            const int kk = ct * 16 + quad * 4 + r;
            // med3/min top-2 update — selection-identical to the strict-< 
            // if/else chain (incl. ties -> keep incumbent / smaller index).
            {
                const float sc = hn[r] - (a0h[r] + a0l[r] * 4.8828125e-4f);
                const bool c1 = sc < v1[0];
                const bool c2 = sc < v2[0];
                const int nk2 = c1 ? k1[0] : (c2 ? kk : k2[0]);
                const int nk1 = c1 ? kk : k1[0];
                v2[0] = __builtin_amdgcn_fmed3f(v1[0], v2[0], sc);
                v1[0] = fminf(v1[0], sc);
                k1[0] = nk1; k2[0] = nk2;
            }
            {
                const float sc = hn[r] - (a1h[r] + a1l[r] * 4.8828125e-4f);
                const bool c1 = sc < v1[1];
                const bool c2 = sc < v2[1];
                const int nk2 = c1 ? k1[1] : (c2 ? kk : k2[1]);
                const int nk1 = c1 ? kk : k1[1];
                v2[1] = __builtin_amdgcn_fmed3f(v1[1], v2[1], sc);
                v1[1] = fminf(v1[1], sc);
                k1[1] = nk1; k2[1] = nk2;
            }
        }

        Ah0 = nAh0; Ah1 = nAh1; Al0 = nAl0; Al1 = nAl1;
    }

    // Cross-quad top-2 merge (lanes l, l^16, l^32 share pixel-col) — R0 verbatim
#pragma unroll
    for (int tt = 0; tt < 2; ++tt) {
#pragma unroll
        for (int off = 16; off <= 32; off <<= 1) {
            float w1 = __shfl_xor(v1[tt], off, 64); int j1 = __shfl_xor(k1[tt], off, 64);
            float w2 = __shfl_xor(v2[tt], off, 64); int j2 = __shfl_xor(k2[tt], off, 64);
            bool aF = (v1[tt] < w1) || (v1[tt] == w1 && k1[tt] < j1);
            float t1 = aF ? v1[tt] : w1;  int u1 = aF ? k1[tt] : j1;
            float tl = aF ? w1 : v1[tt];  int ul = aF ? j1 : k1[tt];      // loser of firsts
            bool bS = (v2[tt] < w2) || (v2[tt] == w2 && k2[tt] < j2);
            float tc = bS ? v2[tt] : w2;  int uc = bS ? k2[tt] : j2;      // better of seconds
            bool lS = (tl < tc) || (tl == tc && ul < uc);
            v1[tt] = t1; k1[tt] = u1;
            v2[tt] = lS ? tl : tc; k2[tt] = lS ? ul : uc;
        }
    }

    // Pixel q = lane&31; lanes l and l+32 handle the same pixel (tt = (l>>4)&1).
    const int q    = lane & 31;
    const int pp   = p0 + q;
    const int tsel = (lane >> 4) & 1;
    const int kA = tsel ? k1[1] : k1[0];
    const int kB = tsel ? k2[1] : k2[0];

    // Exact fp32 rescore, split: lanes<32 score kA, lanes>=32 score kB.
    // Streaming x loads — ops and order bitwise == the passing kernels.
    const int kMine = (lane < 32) ? kA : kB;
    const float4* eM = (const float4*)(emb + kMine * DDIM);
    float a0 = hn_lds[kMine], a1 = 0.f, a2 = 0.f, a3 = 0.f;
#pragma unroll
    for (int i = 0; i < 16; ++i) {
        float4 ea = eM[i];
        const int c = i * 4;
        float x0 = xb[(c + 0) * HW + pp];
        float x1 = xb[(c + 1) * HW + pp];
        float x2 = xb[(c + 2) * HW + pp];
        float x3 = xb[(c + 3) * HW + pp];
        a0 = fmaf(-x0, ea.x, a0);
        a1 = fmaf(-x1, ea.y, a1);
        a2 = fmaf(-x2, ea.z, a2);
        a3 = fmaf(-x3, ea.w, a3);
    }
    const float dMine = (a0 + a1) + (a2 + a3);
    const float dOth  = __shfl_xor(dMine, 32, 64);
    const float dA = (lane < 32) ? dMine : dOth;
    const float dB = (lane < 32) ? dOth  : dMine;
    const int myk = (dB < dA || (dB == dA && kB < kA)) ? kB : kA;

    float lsum = 0.f;
    if (lane < 32) {
        dout[IDX_OFF + b * HW + pp] = (float)myk;
        atomicAdd(&hist[myk], 1);
        const float4* qrow = (const float4*)(emb + myk * DDIM);
        float* ob = dout + OUT_OFF + b * BSTRIDE;
#pragma unroll
        for (int i = 0; i < 16; ++i) {
            float4 qv = qrow[i];
            const int c = i * 4;
            float x0 = xb[(c + 0) * HW + pp];   // L1-warm reload (just read above)
            float x1 = xb[(c + 1) * HW + pp];
            float x2 = xb[(c + 2) * HW + pp];
            float x3 = xb[(c + 3) * HW + pp];
            float d0 = qv.x - x0;
            float d1 = qv.y - x1;
            float d2 = qv.z - x2;
            float d3 = qv.w - x3;
            lsum += d0 * d0 + d1 * d1 + d2 * d2 + d3 * d3;
            ob[(c + 0) * HW + pp] = x0 + d0;    // reference rounding: x + (q - x)
            ob[(c + 1) * HW + pp] = x1 + d1;
            ob[(c + 2) * HW + pp] = x2 + d2;
            ob[(c + 3) * HW + pp] = x3 + d3;
        }
    }
    for (int off = 32; off > 0; off >>= 1) lsum += __shfl_down(lsum, off, 64);
    if (lane == 0) atomicAdd(loss_acc, lsum);

    __syncthreads();
    if (t < KEMB) {
        int v = hist[t];
        if (v) atomicAdd(&counts[t], v);
    }

    // ---- Fused finalize, fence-LESS (R6/R8-proven): __syncthreads() drains
    // each wave's vmcnt before s_barrier, so this block's counts/loss atomics
    // have committed at the device coherence point before t==0 issues the
    // ticket. All cross-block state is atomic-only — no __threadfence.
    __syncthreads();
    if (t == 0) lastflag = (atomicAdd(done_ctr, 1) == 255) ? 1 : 0;
    __syncthreads();
    if (lastflag) {
        if (t < KEMB) {
            int cnt = atomicAdd(&counts[t], 0);   // device-coherent read
            float pa = (float)cnt / (float)NPIX;
            float v = pa * logf(pa + 1e-10f);
#pragma unroll
            for (int off = 1; off <= 32; off <<= 1) v += __shfl_xor(v, off, 64);
            if ((t & 63) == 0) part[t >> 6] = v;
        }
        __syncthreads();
        if (t == 0) {
            float s = 0.f;
#pragma unroll
            for (int i = 0; i < 8; ++i) s += part[i];
            dout[PERP_OFF] = expf(-s);
            dout[0] = 0.25f * atomicAdd(loss_acc, 0.0f) / 8388608.0f;
        }
    }
}

extern "C" void kernel_launch(void* const* d_in, const int* in_sizes, int n_in,
                              void* d_out, int out_size, void* d_ws, size_t ws_size,
                              hipStream_t stream) {
    const float* in  = (const float*)d_in[0];   // 8388608 elems
    const float* emb = (const float*)d_in[1];   // 32768 elems
    float* dout = (float*)d_out;
    int*   counts   = (int*)d_ws;
    float* hnorms   = (float*)((char*)d_ws + 2048);
    float* loss_acc = (float*)((char*)d_ws + 4096);
    int*   done_ctr = (int*)((char*)d_ws + 4160);
    unsigned short* eh_t = (unsigned short*)((char*)d_ws + 8192);
    unsigned short* el_t = eh_t + KEMB * DDIM;   // 64 KB scaled-l table

    vq_init<<<512, 64, 0, stream>>>(emb, counts, hnorms, loss_acc, done_ctr, eh_t, el_t);
    vq_main<<<256, 1024, 0, stream>>>(in, emb, eh_t, el_t, hnorms, counts, loss_acc, done_ctr, dout);
}